// Round 1
// baseline (172.517 us; speedup 1.0000x reference)
//
#include <hip/hip_runtime.h>

// B=16, N=128, E=127, M=16; BN=2048, BNE=260096
#define E_ 127
#define NB 8          // nodes per block in msg_kernel
// out0: BNE*16 = 4,161,536 floats (= 1,040,384 float4)
// out1: BNE*48 = 12,484,608 floats
#define OUT0_F4 1040384
#define O0_PER_NODE_F4 508    // E*16/4
#define O1_PER_NODE_F4 1524   // E*48/4

__device__ __forceinline__ float red32(float v) {
    v += __shfl_xor(v, 1, 32);
    v += __shfl_xor(v, 2, 32);
    v += __shfl_xor(v, 4, 32);
    v += __shfl_xor(v, 8, 32);
    v += __shfl_xor(v, 16, 32);
    return v;
}

__global__ __launch_bounds__(256) void msg_kernel(
    const float* __restrict__ r,   const float* __restrict__ src0, const float* __restrict__ src1,
    const float* __restrict__ b00, const float* __restrict__ b01,
    const float* __restrict__ b10, const float* __restrict__ b11,
    const float* __restrict__ w1,  const float* __restrict__ bb1,
    const float* __restrict__ g1,  const float* __restrict__ be1,
    const float* __restrict__ w2,  const float* __restrict__ bb2,
    const float* __restrict__ g2,  const float* __restrict__ be2,
    const float* __restrict__ w300, const float* __restrict__ b300,
    const float* __restrict__ w301, const float* __restrict__ b301,
    const float* __restrict__ w310, const float* __restrict__ b310,
    const float* __restrict__ w311, const float* __restrict__ b311,
    float* __restrict__ msg_out)
{
    __shared__ float s0s[NB][16];
    __shared__ float s1s[NB][48];
    __shared__ float t1s[NB][16];
    __shared__ float us[NB][3][16][3];
    __shared__ float b00s[NB];
    __shared__ float b01s[NB][3];
    __shared__ float b10s[NB][3];
    __shared__ float b11s[NB][27];
    __shared__ float feats[NB];
    __shared__ float h2s[4][NB][32];
    __shared__ float Rl[NB][1537];   // 1536 R values per node, +1 pad for banks

    const int tid = threadIdx.x;
    const int n0 = blockIdx.x * NB;

    // ---- load per-node inputs (first edge of each node) ----
    for (int idx = tid; idx < NB * 16; idx += 256) {
        int nn = idx >> 4, m = idx & 15;
        s0s[nn][m] = src0[(size_t)(n0 + nn) * E_ * 16 + m];
    }
    for (int idx = tid; idx < NB * 48; idx += 256) {
        int nn = idx / 48, j = idx % 48;
        s1s[nn][j] = src1[(size_t)(n0 + nn) * E_ * 48 + j];
    }
    if (tid < NB) {
        b00s[tid]  = b00[n0 + tid];
        feats[tid] = r[(size_t)(n0 + tid) * E_];
    }
    if (tid >= 32 && tid < 32 + NB * 3) {
        int q = tid - 32; int nn = q / 3, d = q % 3;
        b01s[nn][d] = b01[(size_t)(n0 + nn) * 3 + d];
    }
    if (tid >= 64 && tid < 64 + NB * 3) {
        int q = tid - 64; int nn = q / 3, c = q % 3;
        b10s[nn][c] = b10[(size_t)(n0 + nn) * 3 + c];
    }
    for (int idx = tid; idx < NB * 27; idx += 256) {
        int nn = idx / 27, q = idx % 27;
        b11s[nn][q] = b11[(size_t)(n0 + nn) * 27 + q];
    }
    __syncthreads();

    // ---- t1[i] = sum_c basis10[c]*s1[i*3+c];  u[d][i][f] = sum_c basis11[d,c,f]*s1[i*3+c] ----
    for (int idx = tid; idx < NB * 16; idx += 256) {
        int nn = idx >> 4, i = idx & 15;
        t1s[nn][i] = b10s[nn][0] * s1s[nn][i*3]
                   + b10s[nn][1] * s1s[nn][i*3+1]
                   + b10s[nn][2] * s1s[nn][i*3+2];
    }
    for (int idx = tid; idx < NB * 144; idx += 256) {
        int nn = idx / 144, q = idx % 144;
        int d = q / 48, q2 = q % 48, i = q2 / 3, f = q2 % 3;
        float a = 0.f;
        #pragma unroll
        for (int c = 0; c < 3; ++c) a += b11s[nn][d*9 + c*3 + f] * s1s[nn][i*3 + c];
        us[nn][d][i][f] = a;
    }

    // ---- radial MLPs: group of 32 lanes per node, loop over the 4 nets ----
    {
        const int g = tid >> 5;   // node index within block
        const int j = tid & 31;   // channel
        #pragma unroll
        for (int p = 0; p < 4; ++p) {
            float h = feats[g] * w1[p*32 + j] + bb1[p*32 + j];
            float mu = red32(h) * (1.0f/32.0f);
            float dv = h - mu;
            float var = red32(dv*dv) * (1.0f/32.0f);
            float x = dv * rsqrtf(var + 1e-5f) * g1[p*32 + j] + be1[p*32 + j];
            float h1n = fmaxf(x, 0.0f);

            const float4* w2v = (const float4*)(w2 + p*1024 + j*32);
            float acc = bb2[p*32 + j];
            #pragma unroll
            for (int k4 = 0; k4 < 8; ++k4) {
                float4 w = w2v[k4];
                acc += __shfl(h1n, 4*k4 + 0, 32) * w.x;
                acc += __shfl(h1n, 4*k4 + 1, 32) * w.y;
                acc += __shfl(h1n, 4*k4 + 2, 32) * w.z;
                acc += __shfl(h1n, 4*k4 + 3, 32) * w.w;
            }
            mu = red32(acc) * (1.0f/32.0f);
            dv = acc - mu;
            var = red32(dv*dv) * (1.0f/32.0f);
            x = dv * rsqrtf(var + 1e-5f) * g2[p*32 + j] + be2[p*32 + j];
            h2s[p][g][j] = fmaxf(x, 0.0f);
        }
    }
    __syncthreads();

    // ---- R = W3 @ h2 for all 8 nodes (each thread owns 6 rows, reuses them over nodes) ----
    for (int rr = 0; rr < 6; ++rr) {
        int idx = tid + rr * 256;  // 0..1535, p uniform per wave
        const float* W; const float* Bv; int p, row;
        if (idx < 256)      { p = 0; row = idx;       W = w300; Bv = b300; }
        else if (idx < 512) { p = 1; row = idx - 256; W = w301; Bv = b301; }
        else if (idx < 768) { p = 2; row = idx - 512; W = w310; Bv = b310; }
        else                { p = 3; row = idx - 768; W = w311; Bv = b311; }
        const float4* wv = (const float4*)(W + row * 32);
        float4 a0 = wv[0], a1 = wv[1], a2 = wv[2], a3 = wv[3];
        float4 a4 = wv[4], a5 = wv[5], a6 = wv[6], a7 = wv[7];
        float bb = Bv[row];
        #pragma unroll
        for (int nn = 0; nn < NB; ++nn) {
            const float* h = h2s[p][nn];
            float acc = bb;
            acc += a0.x*h[0]  + a0.y*h[1]  + a0.z*h[2]  + a0.w*h[3];
            acc += a1.x*h[4]  + a1.y*h[5]  + a1.z*h[6]  + a1.w*h[7];
            acc += a2.x*h[8]  + a2.y*h[9]  + a2.z*h[10] + a2.w*h[11];
            acc += a3.x*h[12] + a3.y*h[13] + a3.z*h[14] + a3.w*h[15];
            acc += a4.x*h[16] + a4.y*h[17] + a4.z*h[18] + a4.w*h[19];
            acc += a5.x*h[20] + a5.y*h[21] + a5.z*h[22] + a5.w*h[23];
            acc += a6.x*h[24] + a6.y*h[25] + a6.z*h[26] + a6.w*h[27];
            acc += a7.x*h[28] + a7.y*h[29] + a7.z*h[30] + a7.w*h[31];
            Rl[nn][idx] = acc;   // consecutive idx across lanes: conflict-free
        }
    }
    __syncthreads();

    // ---- contractions -> msg0[16], msg1[48] per node ----
    // msg0[o]      = b00 * sum_i R00[o*16+i]*s0[i]  +  sum_i R10[o*16+i]*t1[i]
    // msg1[o*3+d]  = b01[d] * sum_i R01[o*16+i]*s0[i]
    //              + sum_{i,f} R11[(o*16+i)*3+f] * u[d][i][f]
    for (int pair = tid; pair < 512; pair += 256) {
        if (pair < 128) {
            int o = pair >> 3, nn = pair & 7;
            const float* Rn = Rl[nn];
            float acc0 = 0.f, acc2 = 0.f;
            #pragma unroll
            for (int i = 0; i < 16; ++i) {
                acc0 += Rn[o*16 + i]       * s0s[nn][i];
                acc2 += Rn[512 + o*16 + i] * t1s[nn][i];
            }
            msg_out[(size_t)(n0 + nn) * 64 + o] = b00s[nn] * acc0 + acc2;
        } else {
            int q = pair - 128;
            int od = q >> 3, nn = q & 7;   // od = o*3+d in 0..47
            int o = od / 3, d = od % 3;
            const float* Rn = Rl[nn];
            float acc1 = 0.f, acc3 = 0.f;
            #pragma unroll
            for (int i = 0; i < 16; ++i) {
                acc1 += Rn[256 + o*16 + i] * s0s[nn][i];
                #pragma unroll
                for (int f = 0; f < 3; ++f)
                    acc3 += Rn[768 + (o*16 + i)*3 + f] * us[nn][d][i][f];
            }
            msg_out[(size_t)(n0 + nn) * 64 + 16 + od] = b01s[nn][d] * acc1 + acc3;
        }
    }
}

// ---- broadcast per-node msg to all E edges; pure write-BW kernel ----
__global__ __launch_bounds__(256) void bcast_kernel(const float* __restrict__ msg,
                                                    float* __restrict__ out)
{
    __shared__ float4 m0v[4];    // msg0: 16 floats
    __shared__ float4 m1v[12];   // msg1: 48 floats
    const int n = blockIdx.x;
    const int tid = threadIdx.x;
    if (tid < 16) {
        float4 v = ((const float4*)(msg + (size_t)n * 64))[tid];
        if (tid < 4) m0v[tid] = v; else m1v[tid - 4] = v;
    }
    __syncthreads();

    float4* o0 = (float4*)out + (size_t)n * O0_PER_NODE_F4;
    for (int k = tid; k < O0_PER_NODE_F4; k += 256)
        o0[k] = m0v[k & 3];                 // n*508 % 4 == 0

    float4* o1 = (float4*)out + OUT0_F4 + (size_t)n * O1_PER_NODE_F4;
    for (int k = tid; k < O1_PER_NODE_F4; k += 256)
        o1[k] = m1v[k % 12];                // n*1524 % 12 == 0
}

extern "C" void kernel_launch(void* const* d_in, const int* in_sizes, int n_in,
                              void* d_out, int out_size, void* d_ws, size_t ws_size,
                              hipStream_t stream)
{
    const float* r    = (const float*)d_in[0];
    const float* src0 = (const float*)d_in[1];
    const float* src1 = (const float*)d_in[2];
    const float* b00  = (const float*)d_in[3];
    const float* b01  = (const float*)d_in[4];
    const float* b10  = (const float*)d_in[5];
    const float* b11  = (const float*)d_in[6];
    const float* w1   = (const float*)d_in[7];
    const float* bb1  = (const float*)d_in[8];
    const float* g1   = (const float*)d_in[9];
    const float* be1  = (const float*)d_in[10];
    const float* w2   = (const float*)d_in[11];
    const float* bb2  = (const float*)d_in[12];
    const float* g2   = (const float*)d_in[13];
    const float* be2  = (const float*)d_in[14];
    const float* w300 = (const float*)d_in[15];
    const float* b300 = (const float*)d_in[16];
    const float* w301 = (const float*)d_in[17];
    const float* b301 = (const float*)d_in[18];
    const float* w310 = (const float*)d_in[19];
    const float* b310 = (const float*)d_in[20];
    const float* w311 = (const float*)d_in[21];
    const float* b311 = (const float*)d_in[22];

    float* msg = (float*)d_ws;  // 2048 * 64 floats = 512 KB

    msg_kernel<<<256, 256, 0, stream>>>(r, src0, src1, b00, b01, b10, b11,
        w1, bb1, g1, be1, w2, bb2, g2, be2,
        w300, b300, w301, b301, w310, b310, w311, b311, msg);

    bcast_kernel<<<2048, 256, 0, stream>>>(msg, (float*)d_out);
}

// Round 3
// 163.472 us; speedup vs baseline: 1.0553x; 1.0553x over previous
//
#include <hip/hip_runtime.h>

// B=16, N=128, E=127, M=16; BN=2048, BNE=260096
#define E_ 127
#define NB 4          // nodes per block (fused kernel), 512 blocks total
// out0: BNE*16 = 4,161,536 floats (= 1,040,384 float4)
// out1: BNE*48 = 12,484,608 floats
#define OUT0_F4 1040384
#define O0_PER_NODE_F4 508    // E*16/4
#define O1_PER_NODE_F4 1524   // E*48/4

__device__ __forceinline__ float red32(float v) {
    v += __shfl_xor(v, 1, 32);
    v += __shfl_xor(v, 2, 32);
    v += __shfl_xor(v, 4, 32);
    v += __shfl_xor(v, 8, 32);
    v += __shfl_xor(v, 16, 32);
    return v;
}

__global__ __launch_bounds__(256) void fused_kernel(
    const float* __restrict__ r,   const float* __restrict__ src0, const float* __restrict__ src1,
    const float* __restrict__ b00, const float* __restrict__ b01,
    const float* __restrict__ b10, const float* __restrict__ b11,
    const float* __restrict__ w1,  const float* __restrict__ bb1,
    const float* __restrict__ g1,  const float* __restrict__ be1,
    const float* __restrict__ w2,  const float* __restrict__ bb2,
    const float* __restrict__ g2,  const float* __restrict__ be2,
    const float* __restrict__ w300, const float* __restrict__ b300,
    const float* __restrict__ w301, const float* __restrict__ b301,
    const float* __restrict__ w310, const float* __restrict__ b310,
    const float* __restrict__ w311, const float* __restrict__ b311,
    float* __restrict__ out)
{
    __shared__ float s0s[NB][16];
    __shared__ float s1s[NB][48];
    __shared__ float t1s[NB][16];
    __shared__ float us[NB][3][16][3];
    __shared__ float b00s[NB];
    __shared__ float b01s[NB][3];
    __shared__ float b10s[NB][3];
    __shared__ float b11s[NB][27];
    __shared__ float feats[NB];
    __shared__ float h2s[4][NB][32];
    __shared__ float Rl[NB][1537];   // 1536 R values per node, +1 pad
    __shared__ float msgs[NB][64];   // msg0[16] + msg1[48] per node

    const int tid = threadIdx.x;
    const int n0 = blockIdx.x * NB;

    // ---- load per-node inputs (first edge of each node) ----
    if (tid < NB * 16) {
        int nn = tid >> 4, m = tid & 15;
        s0s[nn][m] = src0[(size_t)(n0 + nn) * E_ * 16 + m];
    }
    if (tid >= 64 && tid < 64 + NB * 48) {
        int q = tid - 64; int nn = q / 48, j = q % 48;
        s1s[nn][j] = src1[(size_t)(n0 + nn) * E_ * 48 + j];
    }
    if (tid < NB) {
        b00s[tid]  = b00[n0 + tid];
        feats[tid] = r[(size_t)(n0 + tid) * E_];
    }
    if (tid >= 8 && tid < 8 + NB * 3) {
        int q = tid - 8; int nn = q / 3, d = q % 3;
        b01s[nn][d] = b01[(size_t)(n0 + nn) * 3 + d];
    }
    if (tid >= 24 && tid < 24 + NB * 3) {
        int q = tid - 24; int nn = q / 3, c = q % 3;
        b10s[nn][c] = b10[(size_t)(n0 + nn) * 3 + c];
    }
    if (tid >= 40 && tid < 40 + NB * 27) {
        int q = tid - 40; int nn = q / 27, qq = q % 27;
        b11s[nn][qq] = b11[(size_t)(n0 + nn) * 27 + qq];
    }
    __syncthreads();

    // ---- t1[i] = sum_c basis10[c]*s1[i*3+c];  u[d][i][f] = sum_c basis11[d,c,f]*s1[i*3+c] ----
    if (tid < NB * 16) {
        int nn = tid >> 4, i = tid & 15;
        t1s[nn][i] = b10s[nn][0] * s1s[nn][i*3]
                   + b10s[nn][1] * s1s[nn][i*3+1]
                   + b10s[nn][2] * s1s[nn][i*3+2];
    }
    // NB*144 = 576 items > 256 threads: MUST be a strided loop (R2 bug was a
    // single-if guard that left 384 of these uninitialized).
    for (int idx = tid; idx < NB * 144; idx += 256) {
        int nn = idx / 144, qq = idx % 144;
        int d = qq / 48, q2 = qq % 48, i = q2 / 3, f = q2 % 3;
        float a = 0.f;
        #pragma unroll
        for (int c = 0; c < 3; ++c) a += b11s[nn][d*9 + c*3 + f] * s1s[nn][i*3 + c];
        us[nn][d][i][f] = a;
    }

    // ---- radial MLPs: 8 groups of 32 lanes; group g -> node g>>1, nets {2*(g&1), 2*(g&1)+1} ----
    {
        const int g = tid >> 5;
        const int j = tid & 31;
        const int nn = g >> 1;
        const int p0 = (g & 1) * 2;
        #pragma unroll
        for (int pi = 0; pi < 2; ++pi) {
            const int p = p0 + pi;
            float h = feats[nn] * w1[p*32 + j] + bb1[p*32 + j];
            float mu = red32(h) * (1.0f/32.0f);
            float dv = h - mu;
            float var = red32(dv*dv) * (1.0f/32.0f);
            float x = dv * rsqrtf(var + 1e-5f) * g1[p*32 + j] + be1[p*32 + j];
            float h1n = fmaxf(x, 0.0f);

            const float4* w2v = (const float4*)(w2 + p*1024 + j*32);
            float acc = bb2[p*32 + j];
            #pragma unroll
            for (int k4 = 0; k4 < 8; ++k4) {
                float4 w = w2v[k4];
                acc += __shfl(h1n, 4*k4 + 0, 32) * w.x;
                acc += __shfl(h1n, 4*k4 + 1, 32) * w.y;
                acc += __shfl(h1n, 4*k4 + 2, 32) * w.z;
                acc += __shfl(h1n, 4*k4 + 3, 32) * w.w;
            }
            mu = red32(acc) * (1.0f/32.0f);
            dv = acc - mu;
            var = red32(dv*dv) * (1.0f/32.0f);
            x = dv * rsqrtf(var + 1e-5f) * g2[p*32 + j] + be2[p*32 + j];
            h2s[p][nn][j] = fmaxf(x, 0.0f);
        }
    }
    __syncthreads();

    // ---- R = W3 @ h2 for all NB nodes (each thread owns 6 rows, reuses them over nodes) ----
    for (int rr = 0; rr < 6; ++rr) {
        int idx = tid + rr * 256;  // 0..1535, p uniform per wave
        const float* W; const float* Bv; int p, row;
        if (idx < 256)      { p = 0; row = idx;       W = w300; Bv = b300; }
        else if (idx < 512) { p = 1; row = idx - 256; W = w301; Bv = b301; }
        else if (idx < 768) { p = 2; row = idx - 512; W = w310; Bv = b310; }
        else                { p = 3; row = idx - 768; W = w311; Bv = b311; }
        const float4* wv = (const float4*)(W + row * 32);
        float4 a0 = wv[0], a1 = wv[1], a2 = wv[2], a3 = wv[3];
        float4 a4 = wv[4], a5 = wv[5], a6 = wv[6], a7 = wv[7];
        float bb = Bv[row];
        #pragma unroll
        for (int nn = 0; nn < NB; ++nn) {
            const float* h = h2s[p][nn];
            float acc = bb;
            acc += a0.x*h[0]  + a0.y*h[1]  + a0.z*h[2]  + a0.w*h[3];
            acc += a1.x*h[4]  + a1.y*h[5]  + a1.z*h[6]  + a1.w*h[7];
            acc += a2.x*h[8]  + a2.y*h[9]  + a2.z*h[10] + a2.w*h[11];
            acc += a3.x*h[12] + a3.y*h[13] + a3.z*h[14] + a3.w*h[15];
            acc += a4.x*h[16] + a4.y*h[17] + a4.z*h[18] + a4.w*h[19];
            acc += a5.x*h[20] + a5.y*h[21] + a5.z*h[22] + a5.w*h[23];
            acc += a6.x*h[24] + a6.y*h[25] + a6.z*h[26] + a6.w*h[27];
            acc += a7.x*h[28] + a7.y*h[29] + a7.z*h[30] + a7.w*h[31];
            Rl[nn][idx] = acc;   // consecutive idx across lanes: conflict-free
        }
    }
    __syncthreads();

    // ---- contractions -> msgs[nn][0..15]=msg0, msgs[nn][16..63]=msg1; exactly 256 items ----
    // msg0[o]      = b00 * sum_i R00[o*16+i]*s0[i]  +  sum_i R10[o*16+i]*t1[i]
    // msg1[o*3+d]  = b01[d] * sum_i R01[o*16+i]*s0[i] + sum_{i,f} R11[(o*16+i)*3+f]*u[d][i][f]
    {
        const int pair = tid;
        if (pair < 64) {
            int o = pair >> 2, nn = pair & 3;
            const float* Rn = Rl[nn];
            float acc0 = 0.f, acc2 = 0.f;
            #pragma unroll
            for (int i = 0; i < 16; ++i) {
                acc0 += Rn[o*16 + i]       * s0s[nn][i];
                acc2 += Rn[512 + o*16 + i] * t1s[nn][i];
            }
            msgs[nn][o] = b00s[nn] * acc0 + acc2;
        } else {
            int q = pair - 64;
            int od = q >> 2, nn = q & 3;   // od = o*3+d in 0..47
            int o = od / 3, d = od % 3;
            const float* Rn = Rl[nn];
            float acc1 = 0.f, acc3 = 0.f;
            #pragma unroll
            for (int i = 0; i < 16; ++i) {
                acc1 += Rn[256 + o*16 + i] * s0s[nn][i];
                #pragma unroll
                for (int f = 0; f < 3; ++f)
                    acc3 += Rn[768 + (o*16 + i)*3 + f] * us[nn][d][i][f];
            }
            msgs[nn][16 + od] = b01s[nn][d] * acc1 + acc3;
        }
    }
    __syncthreads();

    // ---- broadcast write: per node, E copies of msg0 (16f) and msg1 (48f) ----
    const float4* mv = (const float4*)&msgs[0][0];   // [NB][16] float4
    #pragma unroll
    for (int nn = 0; nn < NB; ++nn) {
        const int node = n0 + nn;
        float4* o0 = (float4*)out + (size_t)node * O0_PER_NODE_F4;
        for (int k = tid; k < O0_PER_NODE_F4; k += 256)
            o0[k] = mv[nn*16 + (k & 3)];             // node*508 % 4 == 0
        float4* o1 = (float4*)out + OUT0_F4 + (size_t)node * O1_PER_NODE_F4;
        for (int k = tid; k < O1_PER_NODE_F4; k += 256)
            o1[k] = mv[nn*16 + 4 + (k % 12)];        // node*1524 % 12 == 0
    }
}

extern "C" void kernel_launch(void* const* d_in, const int* in_sizes, int n_in,
                              void* d_out, int out_size, void* d_ws, size_t ws_size,
                              hipStream_t stream)
{
    const float* r    = (const float*)d_in[0];
    const float* src0 = (const float*)d_in[1];
    const float* src1 = (const float*)d_in[2];
    const float* b00  = (const float*)d_in[3];
    const float* b01  = (const float*)d_in[4];
    const float* b10  = (const float*)d_in[5];
    const float* b11  = (const float*)d_in[6];
    const float* w1   = (const float*)d_in[7];
    const float* bb1  = (const float*)d_in[8];
    const float* g1   = (const float*)d_in[9];
    const float* be1  = (const float*)d_in[10];
    const float* w2   = (const float*)d_in[11];
    const float* bb2  = (const float*)d_in[12];
    const float* g2   = (const float*)d_in[13];
    const float* be2  = (const float*)d_in[14];
    const float* w300 = (const float*)d_in[15];
    const float* b300 = (const float*)d_in[16];
    const float* w301 = (const float*)d_in[17];
    const float* b301 = (const float*)d_in[18];
    const float* w310 = (const float*)d_in[19];
    const float* b310 = (const float*)d_in[20];
    const float* w311 = (const float*)d_in[21];
    const float* b311 = (const float*)d_in[22];

    fused_kernel<<<512, 256, 0, stream>>>(r, src0, src1, b00, b01, b10, b11,
        w1, bb1, g1, be1, w2, bb2, g2, be2,
        w300, b300, w301, b301, w310, b310, w311, b311, (float*)d_out);
}